// Round 17
// baseline (450.067 us; speedup 1.0000x reference)
//
#include <hip/hip_runtime.h>

#define NN 20000
#define EE 320000
#define BB 64
#define DD 256
#define DEPTH 3
#define NT (NN + BB)   // h rows + hs rows appended (NT = 20064 = 32*627 = 8*2508)

typedef __attribute__((ext_vector_type(8))) short short8;
typedef __attribute__((ext_vector_type(4))) float floatx4;

// ---------------------------------------------------------------- bf16 split helpers
__device__ __forceinline__ short f2bf(float x) {
  union { float f; unsigned u; } v; v.f = x;
  unsigned r = v.u + 0x7fffu + ((v.u >> 16) & 1u);  // RNE
  return (short)(r >> 16);
}
__device__ __forceinline__ float bf2f(short s) {
  union { unsigned u; float f; } v; v.u = ((unsigned)(unsigned short)s) << 16;
  return v.f;
}

// ---------------------------------------------------------------- reductions
__device__ __forceinline__ float blockSum256(float v, float* tmp) {
  #pragma unroll
  for (int o = 32; o > 0; o >>= 1) v += __shfl_down(v, o, 64);
  if ((threadIdx.x & 63) == 0) tmp[threadIdx.x >> 6] = v;
  __syncthreads();
  float r = tmp[0] + tmp[1] + tmp[2] + tmp[3];
  __syncthreads();
  return r;
}

// ---------------------------------------------------------------- kPre: rank atomics + kM + encode
// SINGLE atomic pass over edges: rank[e] = atomicAdd(curn[dst],1) (round-13: -22us).
// B matrix written in MFMA-FRAGMENT ORDER: Bf[((kc*16+n16)*2+plane)*512 + lane*8+kel],
// lane = kg*16+m16 -- kUpdM's per-wave B fragment load is one coalesced 1KB burst
// (round-15/16 evidence: scattered-line B layout cost 74.5->~44us).
// Blocks: [0,NCB) ranks; [NCB,NCB+512) B; rest encode (wave-per-row).
#define NCB ((EE + 255) / 256)   // 1250
__global__ __launch_bounds__(256) void kPre(const float* __restrict__ X,
                                            const float* __restrict__ Xs,
                                            const float* __restrict__ W1,
                                            float* __restrict__ h,
                                            const int* __restrict__ dst,
                                            const int* __restrict__ bassign,
                                            int* curn, int* curb,
                                            int* __restrict__ rank,
                                            int* __restrict__ rankB,
                                            const float* __restrict__ W2,
                                            const float* __restrict__ W3,
                                            const float* __restrict__ linW,
                                            short* __restrict__ Bf) {
  __shared__ int hb[64], rs[64], hc[64];
  int bid = blockIdx.x, j = threadIdx.x;
  if (bid < NCB) {
    if (j < 64) { hb[j] = 0; hc[j] = 0; }
    __syncthreads();
    int t = bid * 256 + j;
    int b = -1;
    if (t < NN) { b = bassign[t]; atomicAdd(&hb[b], 1); }
    __syncthreads();
    if (j < 64 && hb[j] > 0) rs[j] = atomicAdd(&curb[j], hb[j]);
    __syncthreads();
    if (t < NN) rankB[t] = rs[b] + atomicAdd(&hc[b], 1);
    if (t < EE) rank[t] = atomicAdd(&curn[dst[t]], 1);
  } else if (bid < NCB + 512) {
    // ---- M2 = W2 @ linW[0:256,:], M3 = W3 @ linW[256:512,:], fragment-order split
    int i = (bid - NCB) & 255;
    bool second = (bid - NCB) >= 256;
    const float* W = second ? W3 : W2;
    const float* L = linW + (second ? DD * DD : 0);
    float acc = 0.f;
    #pragma unroll 4
    for (int k = 0; k < DD; k++) acc = fmaf(W[i * DD + k], L[k * DD + j], acc);
    short hi = f2bf(acc);
    short lo = f2bf(acc - bf2f(hi));
    int kk = second ? (DD + i) : i;          // k index in B' (0..511)
    int kc = kk >> 5, kg = (kk >> 3) & 3, kel = kk & 7;
    int n16 = j >> 4, m16 = j & 15;
    size_t idx = ((size_t)(kc * 16 + n16) * 2) * 512 + (kg * 16 + m16) * 8 + kel;
    Bf[idx] = hi;
    Bf[idx + 512] = lo;
  } else {
    int r = (bid - NCB - 512) * 4 + (j >> 6);     // wave-per-row
    int lane = j & 63, c0 = lane * 4;
    const float* x = (r < NN) ? (X + (size_t)r * 2) : (Xs + (size_t)(r - NN) * 2);
    float x0 = x[0], x1 = x[1];
    float4 wa = *(const float4*)(W1 + c0);
    float4 wb = *(const float4*)(W1 + DD + c0);
    float4 v;
    v.x = fmaxf(fmaf(x0, wa.x, x1 * wb.x), 0.f);
    v.y = fmaxf(fmaf(x0, wa.y, x1 * wb.y), 0.f);
    v.z = fmaxf(fmaf(x0, wa.z, x1 * wb.z), 0.f);
    v.w = fmaxf(fmaf(x0, wa.w, x1 * wb.w), 0.f);
    float ss = v.x * v.x + v.y * v.y + v.z * v.z + v.w * v.w;
    #pragma unroll
    for (int o = 1; o < 64; o <<= 1) ss += __shfl_xor(ss, o, 64);
    float inv = 1.f / fmaxf(sqrtf(ss), 1e-12f);
    v.x *= inv; v.y *= inv; v.z *= inv; v.w *= inv;
    *(float4*)(h + (size_t)r * DD + c0) = v;
  }
}

// ---------------------------------------------------------------- CSR scan (counts live in curn/curb)
__global__ __launch_bounds__(1024) void kScan(const int* __restrict__ curn,
                                              int* offn,
                                              const int* __restrict__ curb,
                                              int* offb) {
  __shared__ int sums[1024];
  int t = threadIdx.x;
  const int CH = 20;  // 1024*20 = 20480 >= NN
  int base = t * CH;
  int local[CH];
  int s = 0;
  #pragma unroll
  for (int i = 0; i < CH; i++) {
    int idx = base + i;
    int v = (idx < NN) ? curn[idx] : 0;
    local[i] = s;
    s += v;
  }
  sums[t] = s;
  __syncthreads();
  for (int o = 1; o < 1024; o <<= 1) {
    int x = (t >= o) ? sums[t - o] : 0;
    __syncthreads();
    sums[t] += x;
    __syncthreads();
  }
  int excl = sums[t] - s;
  #pragma unroll
  for (int i = 0; i < CH; i++) {
    int idx = base + i;
    if (idx < NN) offn[idx] = excl + local[i];
  }
  if (t == 1023) offn[NN] = sums[1023];
  // batch offsets: 64-lane shuffle scan (first wave)
  if (t < 64) {
    int v = curb[t];
    int incl = v;
    #pragma unroll
    for (int o = 1; o < 64; o <<= 1) {
      int x = __shfl_up(incl, o, 64);
      if (t >= o) incl += x;
    }
    offb[t] = incl - v;
    if (t == 63) offb[BB] = incl;
  }
}

// ---------------------------------------------------------------- kPlace: rank -> position, no atomics
__global__ __launch_bounds__(256) void kPlace(const int* __restrict__ src,
                                              const int* __restrict__ dst,
                                              const float* __restrict__ w,
                                              const int* __restrict__ bassign,
                                              const int* __restrict__ offn,
                                              const int* __restrict__ offb,
                                              const int* __restrict__ rank,
                                              const int* __restrict__ rankB,
                                              long long* sedge, int* snode) {
  int t = blockIdx.x * 256 + threadIdx.x;
  if (t < EE) {
    unsigned long long e = (unsigned long long)(unsigned)src[t]
                         | ((unsigned long long)(unsigned)__float_as_int(w[t]) << 32);
    sedge[offn[dst[t]] + rank[t]] = (long long)e;
  }
  if (t < NN) snode[offb[bassign[t]] + rankB[t]] = t;
}

// ---------------------------------------------------------------- aggregation (XCD-sliced, 8 waves = 8 nodes)
// STRUCTURAL FLOOR (declared): 2.56M distinct 128B gather lines/dispatch = 10K/CU;
// at ~350cyc L2-hit-under-load and ~32 outstanding L1 misses/CU -> 1 line/10.9cyc
// -> 45.5us model vs ~47 measured. Rounds 7/9/12 structures all converge here.
#define ECAP 1024   // staged edges per chunk (8 KB)
__global__ __launch_bounds__(512) void kAgg(const float* __restrict__ h,
                                            const int* __restrict__ offn,
                                            const long long* __restrict__ sedge,
                                            const int* __restrict__ offb,
                                            const int* __restrict__ snode,
                                            float* __restrict__ hnv) {
  __shared__ __align__(16) long long Led[ECAP];
  int bid = blockIdx.x;
  int slice = bid & 7, group = bid >> 3;      // group 0..2507
  int t = threadIdx.x;
  int w = t >> 6, lane = t & 63;
  int eg = lane >> 3;          // edge group 0..7
  int pc = lane & 7;           // float4 piece 0..7
  int colB = slice * 32 + pc * 4;
  float4 acc = make_float4(0.f, 0.f, 0.f, 0.f);

  if (group < 8) {
    // ---- batch rows: nodes 0..63 (8 per block), snode index list (weight 1)
    int b0 = group * 8;
    int s0 = offb[b0], e0 = offb[b0 + 8];
    int sW = offb[b0 + w], eW = offb[b0 + w + 1];
    int* Li = (int*)Led;
    for (int base = s0; base < e0; base += 2 * ECAP) {
      int cnt = min(e0 - base, 2 * ECAP);
      __syncthreads();
      for (int i = t; i < cnt; i += 512) Li[i] = snode[base + i];
      __syncthreads();
      int lo = max(sW, base), hi = min(eW, base + cnt);
      for (int i = lo; i < hi; i += 16) {
        int i0 = i + eg, i1 = i + 8 + eg;
        int n0 = Li[min(i0, hi - 1) - base];
        int n1 = Li[min(i1, hi - 1) - base];
        float w0 = (i0 < hi) ? 1.f : 0.f;
        float w1 = (i1 < hi) ? 1.f : 0.f;
        float4 v0 = *(const float4*)(h + (size_t)n0 * DD + colB);
        float4 v1 = *(const float4*)(h + (size_t)n1 * DD + colB);
        acc.x = fmaf(w0, v0.x, fmaf(w1, v1.x, acc.x));
        acc.y = fmaf(w0, v0.y, fmaf(w1, v1.y, acc.y));
        acc.z = fmaf(w0, v0.z, fmaf(w1, v1.z, acc.z));
        acc.w = fmaf(w0, v0.w, fmaf(w1, v1.w, acc.w));
      }
    }
    #pragma unroll
    for (int o = 8; o < 64; o <<= 1) {
      acc.x += __shfl_xor(acc.x, o, 64);
      acc.y += __shfl_xor(acc.y, o, 64);
      acc.z += __shfl_xor(acc.z, o, 64);
      acc.w += __shfl_xor(acc.w, o, 64);
    }
    if (eg == 0) *(float4*)(hnv + (size_t)(NN + b0 + w) * DD + colB) = acc;
  } else {
    // ---- edge nodes, 8 per block
    int first = (group - 8) * 8;
    int s0 = offn[first], e0 = offn[first + 8];
    int sW = offn[first + w], eW = offn[first + w + 1];
    for (int base = s0; base < e0; base += ECAP) {
      int cnt = min(e0 - base, ECAP);
      __syncthreads();
      for (int i = t; i < cnt; i += 512) Led[i] = sedge[base + i];
      __syncthreads();
      int lo = max(sW, base), hi = min(eW, base + cnt);
      for (int i = lo; i < hi; i += 16) {
        int i0 = i + eg, i1 = i + 8 + eg;
        long long e0v = Led[min(i0, hi - 1) - base];
        long long e1v = Led[min(i1, hi - 1) - base];
        float w0 = (i0 < hi) ? __int_as_float((int)(e0v >> 32)) : 0.f;
        float w1 = (i1 < hi) ? __int_as_float((int)(e1v >> 32)) : 0.f;
        unsigned r0 = (unsigned)(e0v & 0xffffffffLL);
        unsigned r1 = (unsigned)(e1v & 0xffffffffLL);
        float4 v0 = *(const float4*)(h + (size_t)r0 * DD + colB);
        float4 v1 = *(const float4*)(h + (size_t)r1 * DD + colB);
        acc.x = fmaf(w0, v0.x, fmaf(w1, v1.x, acc.x));
        acc.y = fmaf(w0, v0.y, fmaf(w1, v1.y, acc.y));
        acc.z = fmaf(w0, v0.z, fmaf(w1, v1.z, acc.z));
        acc.w = fmaf(w0, v0.w, fmaf(w1, v1.w, acc.w));
      }
    }
    #pragma unroll
    for (int o = 8; o < 64; o <<= 1) {
      acc.x += __shfl_xor(acc.x, o, 64);
      acc.y += __shfl_xor(acc.y, o, 64);
      acc.z += __shfl_xor(acc.z, o, 64);
      acc.w += __shfl_xor(acc.w, o, 64);
    }
    if (eg == 0) *(float4*)(hnv + (size_t)(first + w) * DD + colB) = acc;
  }
}

// ---------------------------------------------------------------- MFMA dual-GEMM + fused l2norm
// BARRIER-FREE K-LOOP, 8-WAVE BLOCKS: block = 512 threads = 8 waves, each wave owns
// 32 rows x 32 cols (ct=2); block still spans the full 32x256 row panel so the
// l2norm epilogue stays block-local. Waves/CU 9.8 -> 19.6 vs round-16's 4-wave
// blocks (round-16 evidence: kUpdM ~44us, B-latency-bound at 2.45 blocks/CU).
// B fragments: coalesced 1KB bursts from fragment-ordered Bf (L2-resident 512KB);
// A fragments built in-register from fp32 (row lines L1-shared by all 8 waves).
#define TRU 32
__global__ __launch_bounds__(512) void kUpdM(const float* __restrict__ A,
                                             const float* __restrict__ Av,
                                             const short* __restrict__ Bf,
                                             const float* __restrict__ lb,
                                             float* __restrict__ out) {
  __shared__ float ssq[8][TRU];
  const int t = threadIdx.x;
  const int rb = blockIdx.x * TRU;
  const int wid = t >> 6;          // 0..7
  const int lane = t & 63;
  const int wc = wid * 32;         // wave col offset (8 waves cover 256 cols)
  const int m16 = lane & 15;
  const int kg = lane >> 4;        // 0..3

  floatx4 acc[2][2];
  #pragma unroll
  for (int ct = 0; ct < 2; ct++) {
    float b = lb[wc + ct * 16 + m16];
    #pragma unroll
    for (int rt = 0; rt < 2; rt++) acc[rt][ct] = (floatx4){b, b, b, b};
  }

  #pragma unroll 2
  for (int kc = 0; kc < 16; ++kc) {
    const int k0 = kc * 32;
    const float* src = (k0 < DD) ? (A + k0) : (Av + (k0 - DD));
    // ---- A fragments in-register: lane (m16,kg) loads 8 fp32 of row rt*16+m16,
    // k = kg*8..+8, splits to hi/lo bf16. All 8 waves read the same lines (L1).
    short8 ah[2], al_[2];
    #pragma unroll
    for (int rt = 0; rt < 2; rt++) {
      const float* p = src + (size_t)(rb + rt * 16 + m16) * DD + kg * 8;
      float4 u = *(const float4*)p;
      float4 v = *(const float4*)(p + 4);
      float f[8] = {u.x, u.y, u.z, u.w, v.x, v.y, v.z, v.w};
      short8 hi8, lo8;
      #pragma unroll
      for (int q = 0; q < 8; q++) {
        short hi = f2bf(f[q]);
        hi8[q] = hi;
        lo8[q] = f2bf(f[q] - bf2f(hi));
      }
      ah[rt] = hi8;
      al_[rt] = lo8;
    }
    // ---- B fragments: coalesced 1KB bursts from fragment-ordered Bf, then MFMA
    #pragma unroll
    for (int ct = 0; ct < 2; ct++) {
      const short* bp = Bf + ((size_t)(kc * 16 + wid * 2 + ct) * 2) * 512 + lane * 8;
      short8 bh = *(const short8*)bp;
      short8 bl = *(const short8*)(bp + 512);
      #pragma unroll
      for (int rt = 0; rt < 2; rt++) {
        acc[rt][ct] = __builtin_amdgcn_mfma_f32_16x16x32_bf16(ah[rt], bh, acc[rt][ct], 0, 0, 0);
        acc[rt][ct] = __builtin_amdgcn_mfma_f32_16x16x32_bf16(ah[rt], bl, acc[rt][ct], 0, 0, 0);
        acc[rt][ct] = __builtin_amdgcn_mfma_f32_16x16x32_bf16(al_[rt], bh, acc[rt][ct], 0, 0, 0);
      }
    }
  }
  // ---- epilogue: relu + row l2norm + store (C/D: col=lane&15, row=(lane>>4)*4+reg)
  float p[2][4];
  #pragma unroll
  for (int rt = 0; rt < 2; rt++)
    #pragma unroll
    for (int reg = 0; reg < 4; reg++) {
      float s = 0.f;
      #pragma unroll
      for (int ct = 0; ct < 2; ct++) {
        float x = fmaxf(acc[rt][ct][reg], 0.f);
        s = fmaf(x, x, s);
      }
      p[rt][reg] = s;
    }
  #pragma unroll
  for (int o = 1; o < 16; o <<= 1)
    #pragma unroll
    for (int rt = 0; rt < 2; rt++)
      #pragma unroll
      for (int reg = 0; reg < 4; reg++)
        p[rt][reg] += __shfl_xor(p[rt][reg], o, 64);
  if (m16 == 0) {
    #pragma unroll
    for (int rt = 0; rt < 2; rt++)
      #pragma unroll
      for (int reg = 0; reg < 4; reg++)
        ssq[wid][rt * 16 + kg * 4 + reg] = p[rt][reg];
  }
  __syncthreads();
  #pragma unroll
  for (int rt = 0; rt < 2; rt++) {
    #pragma unroll
    for (int reg = 0; reg < 4; reg++) {
      int row = rt * 16 + kg * 4 + reg;
      float ss = 0.f;
      #pragma unroll
      for (int ww = 0; ww < 8; ww++) ss += ssq[ww][row];
      float inv = 1.f / fmaxf(sqrtf(ss), 1e-12f);
      #pragma unroll
      for (int ct = 0; ct < 2; ct++) {
        int col = wc + ct * 16 + m16;
        out[(size_t)(rb + row) * DD + col] = fmaxf(acc[rt][ct][reg], 0.f) * inv;
      }
    }
  }
}

// ---------------------------------------------------------------- decode
__global__ __launch_bounds__(256) void kDec(const float* __restrict__ h,
                                            const int* __restrict__ aidx,
                                            const float* __restrict__ W4,
                                            const float* __restrict__ W5,
                                            float* __restrict__ Q) {
  __shared__ float tmp[4];
  int b = blockIdx.x, j = threadIdx.x;
  float s = blockSum256(h[(size_t)(NN + b) * DD + j] * W4[j], tmp);
  int a = aidx[b];
  float za = h[(size_t)a * DD + j];
  float q = blockSum256(fmaxf(za * s, 0.f) * W5[j], tmp);
  if (j == 0) Q[b] = q;
}

// ---------------------------------------------------------------- launcher
extern "C" void kernel_launch(void* const* d_in, const int* in_sizes, int n_in,
                              void* d_out, int out_size, void* d_ws, size_t ws_size,
                              hipStream_t stream) {
  (void)in_sizes; (void)n_in; (void)out_size; (void)ws_size;
  const int*   edge_src = (const int*)d_in[0];
  const int*   edge_dst = (const int*)d_in[1];
  const float* edge_w   = (const float*)d_in[2];
  const int*   bassign  = (const int*)d_in[3];
  const int*   aidx     = (const int*)d_in[4];
  const float* Xf       = (const float*)d_in[5];
  const float* Xs       = (const float*)d_in[6];
  const float* W1       = (const float*)d_in[7];
  const float* W2       = (const float*)d_in[8];
  const float* W3       = (const float*)d_in[9];
  const float* linW     = (const float*)d_in[10];
  const float* linB     = (const float*)d_in[11];
  const float* W4       = (const float*)d_in[12];
  const float* W5       = (const float*)d_in[13];
  float* Q = (float*)d_out;

  char* base = (char*)d_ws;
  const size_t NB = (size_t)NT * DD * 4;   // rows include hs
  float* hA   = (float*)(base);
  float* hnv  = (float*)(base + NB);
  float* hB   = (float*)(base + 2 * NB);
  size_t o = 3 * NB;
  short* Bf   = (short*)(base + o); o += (size_t)DD * 512 * 2 * 2;  // 512 KB, fragment order
  long long* sedge = (long long*)(base + o); o += (size_t)EE * 8;
  int*   snode= (int*)(base + o);   o += (size_t)NN * 4;
  int*   rank = (int*)(base + o);   o += (size_t)EE * 4;
  int*   rankB= (int*)(base + o);   o += (size_t)NN * 4;
  int*   offn = (int*)(base + o);   o += (size_t)(NN + 4) * 4;
  int*   offb = (int*)(base + o);   o += (size_t)(BB + 4) * 4;
  int*   curn = (int*)(base + o);   o += (size_t)NN * 4;
  int*   curb = (int*)(base + o);   o += (size_t)BB * 4;   // contiguous with curn

  hipMemsetAsync(curn, 0, (size_t)(NN + BB) * 4, stream);

  kPre<<<NCB + 512 + NT / 4, 256, 0, stream>>>(Xf, Xs, W1, hA,
                                               edge_dst, bassign, curn, curb,
                                               rank, rankB,
                                               W2, W3, linW, Bf);
  kScan<<<1, 1024, 0, stream>>>(curn, offn, curb, offb);
  kPlace<<<(EE + 255) / 256, 256, 0, stream>>>(edge_src, edge_dst, edge_w, bassign,
                                               offn, offb, rank, rankB, sedge, snode);
  float* hc = hA;
  float* hn = hB;
  for (int d = 0; d < DEPTH; d++) {
    kAgg<<<8 * (NT / 8), 512, 0, stream>>>(hc, offn, sedge, offb, snode, hnv);
    kUpdM<<<NT / TRU, 512, 0, stream>>>(hc, hnv, Bf, linB, hn);
    float* sw2 = hc; hc = hn; hn = sw2;
  }
  kDec<<<BB, 256, 0, stream>>>(hc, aidx, W4, W5, Q);
}

// Round 18
// 357.187 us; speedup vs baseline: 1.2600x; 1.2600x over previous
//
#include <hip/hip_runtime.h>

#define NN 20000
#define EE 320000
#define BB 64
#define DD 256
#define DEPTH 3
#define NT (NN + BB)   // h rows + hs rows appended (NT = 20064 = 32*627 = 8*2508)

typedef __attribute__((ext_vector_type(8))) short short8;
typedef __attribute__((ext_vector_type(4))) float floatx4;

// ---------------------------------------------------------------- bf16 split helpers
__device__ __forceinline__ short f2bf(float x) {
  union { float f; unsigned u; } v; v.f = x;
  unsigned r = v.u + 0x7fffu + ((v.u >> 16) & 1u);  // RNE
  return (short)(r >> 16);
}
__device__ __forceinline__ float bf2f(short s) {
  union { unsigned u; float f; } v; v.u = ((unsigned)(unsigned short)s) << 16;
  return v.f;
}

// ---------------------------------------------------------------- reductions
__device__ __forceinline__ float blockSum256(float v, float* tmp) {
  #pragma unroll
  for (int o = 32; o > 0; o >>= 1) v += __shfl_down(v, o, 64);
  if ((threadIdx.x & 63) == 0) tmp[threadIdx.x >> 6] = v;
  __syncthreads();
  float r = tmp[0] + tmp[1] + tmp[2] + tmp[3];
  __syncthreads();
  return r;
}

// ---------------------------------------------------------------- kPre: rank atomics + kM + encode
// SINGLE atomic pass over edges: rank[e] = atomicAdd(curn[dst],1) (round-13: -22us).
// B matrix written in MFMA-FRAGMENT ORDER: Bf[((kc*16+n16)*2+plane)*512 + lane*8+kel],
// lane = kg*16+m16 -- kUpdM's per-wave B fragment load is one coalesced 1KB burst
// (round-15/16 evidence: scattered-line B layout cost 74.5->~44us).
// Blocks: [0,NCB) ranks; [NCB,NCB+512) B; rest encode (wave-per-row).
#define NCB ((EE + 255) / 256)   // 1250
__global__ __launch_bounds__(256) void kPre(const float* __restrict__ X,
                                            const float* __restrict__ Xs,
                                            const float* __restrict__ W1,
                                            float* __restrict__ h,
                                            const int* __restrict__ dst,
                                            const int* __restrict__ bassign,
                                            int* curn, int* curb,
                                            int* __restrict__ rank,
                                            int* __restrict__ rankB,
                                            const float* __restrict__ W2,
                                            const float* __restrict__ W3,
                                            const float* __restrict__ linW,
                                            short* __restrict__ Bf) {
  __shared__ int hb[64], rs[64], hc[64];
  int bid = blockIdx.x, j = threadIdx.x;
  if (bid < NCB) {
    if (j < 64) { hb[j] = 0; hc[j] = 0; }
    __syncthreads();
    int t = bid * 256 + j;
    int b = -1;
    if (t < NN) { b = bassign[t]; atomicAdd(&hb[b], 1); }
    __syncthreads();
    if (j < 64 && hb[j] > 0) rs[j] = atomicAdd(&curb[j], hb[j]);
    __syncthreads();
    if (t < NN) rankB[t] = rs[b] + atomicAdd(&hc[b], 1);
    if (t < EE) rank[t] = atomicAdd(&curn[dst[t]], 1);
  } else if (bid < NCB + 512) {
    // ---- M2 = W2 @ linW[0:256,:], M3 = W3 @ linW[256:512,:], fragment-order split
    int i = (bid - NCB) & 255;
    bool second = (bid - NCB) >= 256;
    const float* W = second ? W3 : W2;
    const float* L = linW + (second ? DD * DD : 0);
    float acc = 0.f;
    #pragma unroll 4
    for (int k = 0; k < DD; k++) acc = fmaf(W[i * DD + k], L[k * DD + j], acc);
    short hi = f2bf(acc);
    short lo = f2bf(acc - bf2f(hi));
    int kk = second ? (DD + i) : i;          // k index in B' (0..511)
    int kc = kk >> 5, kg = (kk >> 3) & 3, kel = kk & 7;
    int n16 = j >> 4, m16 = j & 15;
    size_t idx = ((size_t)(kc * 16 + n16) * 2) * 512 + (kg * 16 + m16) * 8 + kel;
    Bf[idx] = hi;
    Bf[idx + 512] = lo;
  } else {
    int r = (bid - NCB - 512) * 4 + (j >> 6);     // wave-per-row
    int lane = j & 63, c0 = lane * 4;
    const float* x = (r < NN) ? (X + (size_t)r * 2) : (Xs + (size_t)(r - NN) * 2);
    float x0 = x[0], x1 = x[1];
    float4 wa = *(const float4*)(W1 + c0);
    float4 wb = *(const float4*)(W1 + DD + c0);
    float4 v;
    v.x = fmaxf(fmaf(x0, wa.x, x1 * wb.x), 0.f);
    v.y = fmaxf(fmaf(x0, wa.y, x1 * wb.y), 0.f);
    v.z = fmaxf(fmaf(x0, wa.z, x1 * wb.z), 0.f);
    v.w = fmaxf(fmaf(x0, wa.w, x1 * wb.w), 0.f);
    float ss = v.x * v.x + v.y * v.y + v.z * v.z + v.w * v.w;
    #pragma unroll
    for (int o = 1; o < 64; o <<= 1) ss += __shfl_xor(ss, o, 64);
    float inv = 1.f / fmaxf(sqrtf(ss), 1e-12f);
    v.x *= inv; v.y *= inv; v.z *= inv; v.w *= inv;
    *(float4*)(h + (size_t)r * DD + c0) = v;
  }
}

// ---------------------------------------------------------------- CSR scan (counts live in curn/curb)
__global__ __launch_bounds__(1024) void kScan(const int* __restrict__ curn,
                                              int* offn,
                                              const int* __restrict__ curb,
                                              int* offb) {
  __shared__ int sums[1024];
  int t = threadIdx.x;
  const int CH = 20;  // 1024*20 = 20480 >= NN
  int base = t * CH;
  int local[CH];
  int s = 0;
  #pragma unroll
  for (int i = 0; i < CH; i++) {
    int idx = base + i;
    int v = (idx < NN) ? curn[idx] : 0;
    local[i] = s;
    s += v;
  }
  sums[t] = s;
  __syncthreads();
  for (int o = 1; o < 1024; o <<= 1) {
    int x = (t >= o) ? sums[t - o] : 0;
    __syncthreads();
    sums[t] += x;
    __syncthreads();
  }
  int excl = sums[t] - s;
  #pragma unroll
  for (int i = 0; i < CH; i++) {
    int idx = base + i;
    if (idx < NN) offn[idx] = excl + local[i];
  }
  if (t == 1023) offn[NN] = sums[1023];
  // batch offsets: 64-lane shuffle scan (first wave)
  if (t < 64) {
    int v = curb[t];
    int incl = v;
    #pragma unroll
    for (int o = 1; o < 64; o <<= 1) {
      int x = __shfl_up(incl, o, 64);
      if (t >= o) incl += x;
    }
    offb[t] = incl - v;
    if (t == 63) offb[BB] = incl;
  }
}

// ---------------------------------------------------------------- kPlace: rank -> position, no atomics
__global__ __launch_bounds__(256) void kPlace(const int* __restrict__ src,
                                              const int* __restrict__ dst,
                                              const float* __restrict__ w,
                                              const int* __restrict__ bassign,
                                              const int* __restrict__ offn,
                                              const int* __restrict__ offb,
                                              const int* __restrict__ rank,
                                              const int* __restrict__ rankB,
                                              long long* sedge, int* snode) {
  int t = blockIdx.x * 256 + threadIdx.x;
  if (t < EE) {
    unsigned long long e = (unsigned long long)(unsigned)src[t]
                         | ((unsigned long long)(unsigned)__float_as_int(w[t]) << 32);
    sedge[offn[dst[t]] + rank[t]] = (long long)e;
  }
  if (t < NN) snode[offb[bassign[t]] + rankB[t]] = t;
}

// ---------------------------------------------------------------- aggregation (XCD-sliced, 8 waves = 8 nodes)
// STRUCTURAL FLOOR (declared): 2.56M distinct 128B gather lines/dispatch = 10K/CU;
// at ~350cyc L2-hit-under-load and ~32 outstanding L1 misses/CU -> 1 line/10.9cyc
// -> 45.5us model vs ~47 measured. Rounds 7/9/12 structures all converge here.
#define ECAP 1024   // staged edges per chunk (8 KB)
__global__ __launch_bounds__(512) void kAgg(const float* __restrict__ h,
                                            const int* __restrict__ offn,
                                            const long long* __restrict__ sedge,
                                            const int* __restrict__ offb,
                                            const int* __restrict__ snode,
                                            float* __restrict__ hnv) {
  __shared__ __align__(16) long long Led[ECAP];
  int bid = blockIdx.x;
  int slice = bid & 7, group = bid >> 3;      // group 0..2507
  int t = threadIdx.x;
  int w = t >> 6, lane = t & 63;
  int eg = lane >> 3;          // edge group 0..7
  int pc = lane & 7;           // float4 piece 0..7
  int colB = slice * 32 + pc * 4;
  float4 acc = make_float4(0.f, 0.f, 0.f, 0.f);

  if (group < 8) {
    // ---- batch rows: nodes 0..63 (8 per block), snode index list (weight 1)
    int b0 = group * 8;
    int s0 = offb[b0], e0 = offb[b0 + 8];
    int sW = offb[b0 + w], eW = offb[b0 + w + 1];
    int* Li = (int*)Led;
    for (int base = s0; base < e0; base += 2 * ECAP) {
      int cnt = min(e0 - base, 2 * ECAP);
      __syncthreads();
      for (int i = t; i < cnt; i += 512) Li[i] = snode[base + i];
      __syncthreads();
      int lo = max(sW, base), hi = min(eW, base + cnt);
      for (int i = lo; i < hi; i += 16) {
        int i0 = i + eg, i1 = i + 8 + eg;
        int n0 = Li[min(i0, hi - 1) - base];
        int n1 = Li[min(i1, hi - 1) - base];
        float w0 = (i0 < hi) ? 1.f : 0.f;
        float w1 = (i1 < hi) ? 1.f : 0.f;
        float4 v0 = *(const float4*)(h + (size_t)n0 * DD + colB);
        float4 v1 = *(const float4*)(h + (size_t)n1 * DD + colB);
        acc.x = fmaf(w0, v0.x, fmaf(w1, v1.x, acc.x));
        acc.y = fmaf(w0, v0.y, fmaf(w1, v1.y, acc.y));
        acc.z = fmaf(w0, v0.z, fmaf(w1, v1.z, acc.z));
        acc.w = fmaf(w0, v0.w, fmaf(w1, v1.w, acc.w));
      }
    }
    #pragma unroll
    for (int o = 8; o < 64; o <<= 1) {
      acc.x += __shfl_xor(acc.x, o, 64);
      acc.y += __shfl_xor(acc.y, o, 64);
      acc.z += __shfl_xor(acc.z, o, 64);
      acc.w += __shfl_xor(acc.w, o, 64);
    }
    if (eg == 0) *(float4*)(hnv + (size_t)(NN + b0 + w) * DD + colB) = acc;
  } else {
    // ---- edge nodes, 8 per block
    int first = (group - 8) * 8;
    int s0 = offn[first], e0 = offn[first + 8];
    int sW = offn[first + w], eW = offn[first + w + 1];
    for (int base = s0; base < e0; base += ECAP) {
      int cnt = min(e0 - base, ECAP);
      __syncthreads();
      for (int i = t; i < cnt; i += 512) Led[i] = sedge[base + i];
      __syncthreads();
      int lo = max(sW, base), hi = min(eW, base + cnt);
      for (int i = lo; i < hi; i += 16) {
        int i0 = i + eg, i1 = i + 8 + eg;
        long long e0v = Led[min(i0, hi - 1) - base];
        long long e1v = Led[min(i1, hi - 1) - base];
        float w0 = (i0 < hi) ? __int_as_float((int)(e0v >> 32)) : 0.f;
        float w1 = (i1 < hi) ? __int_as_float((int)(e1v >> 32)) : 0.f;
        unsigned r0 = (unsigned)(e0v & 0xffffffffLL);
        unsigned r1 = (unsigned)(e1v & 0xffffffffLL);
        float4 v0 = *(const float4*)(h + (size_t)r0 * DD + colB);
        float4 v1 = *(const float4*)(h + (size_t)r1 * DD + colB);
        acc.x = fmaf(w0, v0.x, fmaf(w1, v1.x, acc.x));
        acc.y = fmaf(w0, v0.y, fmaf(w1, v1.y, acc.y));
        acc.z = fmaf(w0, v0.z, fmaf(w1, v1.z, acc.z));
        acc.w = fmaf(w0, v0.w, fmaf(w1, v1.w, acc.w));
      }
    }
    #pragma unroll
    for (int o = 8; o < 64; o <<= 1) {
      acc.x += __shfl_xor(acc.x, o, 64);
      acc.y += __shfl_xor(acc.y, o, 64);
      acc.z += __shfl_xor(acc.z, o, 64);
      acc.w += __shfl_xor(acc.w, o, 64);
    }
    if (eg == 0) *(float4*)(hnv + (size_t)(first + w) * DD + colB) = acc;
  }
}

// ---------------------------------------------------------------- MFMA dual-GEMM + fused l2norm (hybrid)
// 512-thread block, TRU=32 full-width. Per kc: A tile (32x32 fp32) converted ONCE by
// threads 0..255 into padded LDS (row stride 80B -> 16B-aligned b128 reads, worst
// 2-way bank aliasing = free); B fragments direct coalesced 1KB bursts from the
// fragment-ordered Bf (L2-resident 512KB); 12 MFMAs per wave per kc.
// Addresses all four diagnosed kUpdM costs: B scatter (Bf, r15->r16), barrier-coupled
// B staging (direct-B), A-conversion redundancy (LDS-once vs 8x in r17: VALU 28.7%),
// wave starvation (8 waves -> 19.6 waves/CU vs r16's 9.8).
#define TRU 32
__global__ __launch_bounds__(512) void kUpdM(const float* __restrict__ A,
                                             const float* __restrict__ Av,
                                             const short* __restrict__ Bf,
                                             const float* __restrict__ lb,
                                             float* __restrict__ out) {
  __shared__ __align__(16) short Ah[TRU][40];   // 80B row stride: 16B-aligned, 2-way max
  __shared__ __align__(16) short Al[TRU][40];
  __shared__ float ssq[8][TRU];
  const int t = threadIdx.x;
  const int rb = blockIdx.x * TRU;
  const int wid = t >> 6;          // 0..7
  const int lane = t & 63;
  const int wc = wid * 32;         // wave col offset (8 waves cover 256 cols)
  const int m16 = lane & 15;
  const int kg = lane >> 4;        // 0..3

  floatx4 acc[2][2];
  #pragma unroll
  for (int ct = 0; ct < 2; ct++) {
    float b = lb[wc + ct * 16 + m16];
    #pragma unroll
    for (int rt = 0; rt < 2; rt++) acc[rt][ct] = (floatx4){b, b, b, b};
  }

  for (int kc = 0; kc < 16; ++kc) {
    const int k0 = kc * 32;
    const float* src = (k0 < DD) ? (A + k0) : (Av + (k0 - DD));
    // ---- stage A once: threads 0..255 each convert one float4 (32 rows x 8 float4)
    if (t < 256) {
      int r = t >> 3;              // 0..31
      int q = t & 7;               // float4 index within the 32-k chunk
      float4 v = *(const float4*)(src + (size_t)(rb + r) * DD + q * 4);
      short s0 = f2bf(v.x), s1 = f2bf(v.y), s2 = f2bf(v.z), s3 = f2bf(v.w);
      short l0 = f2bf(v.x - bf2f(s0)), l1 = f2bf(v.y - bf2f(s1));
      short l2 = f2bf(v.z - bf2f(s2)), l3 = f2bf(v.w - bf2f(s3));
      uint2 whi, wlo;
      whi.x = (unsigned short)s0 | ((unsigned)(unsigned short)s1 << 16);
      whi.y = (unsigned short)s2 | ((unsigned)(unsigned short)s3 << 16);
      wlo.x = (unsigned short)l0 | ((unsigned)(unsigned short)l1 << 16);
      wlo.y = (unsigned short)l2 | ((unsigned)(unsigned short)l3 << 16);
      *(uint2*)&Ah[r][q * 4] = whi;
      *(uint2*)&Al[r][q * 4] = wlo;
    }
    __syncthreads();
    // ---- A fragments from LDS (b128), B fragments direct from Bf, MFMA
    short8 ah[2], al_[2];
    #pragma unroll
    for (int rt = 0; rt < 2; rt++) {
      ah[rt]  = *(const short8*)&Ah[rt * 16 + m16][kg * 8];
      al_[rt] = *(const short8*)&Al[rt * 16 + m16][kg * 8];
    }
    #pragma unroll
    for (int ct = 0; ct < 2; ct++) {
      const short* bp = Bf + ((size_t)(kc * 16 + wid * 2 + ct) * 2) * 512 + lane * 8;
      short8 bh = *(const short8*)bp;
      short8 bl = *(const short8*)(bp + 512);
      #pragma unroll
      for (int rt = 0; rt < 2; rt++) {
        acc[rt][ct] = __builtin_amdgcn_mfma_f32_16x16x32_bf16(ah[rt], bh, acc[rt][ct], 0, 0, 0);
        acc[rt][ct] = __builtin_amdgcn_mfma_f32_16x16x32_bf16(ah[rt], bl, acc[rt][ct], 0, 0, 0);
        acc[rt][ct] = __builtin_amdgcn_mfma_f32_16x16x32_bf16(al_[rt], bh, acc[rt][ct], 0, 0, 0);
      }
    }
    __syncthreads();
  }
  // ---- epilogue: relu + row l2norm + store (C/D: col=lane&15, row=(lane>>4)*4+reg)
  float p[2][4];
  #pragma unroll
  for (int rt = 0; rt < 2; rt++)
    #pragma unroll
    for (int reg = 0; reg < 4; reg++) {
      float s = 0.f;
      #pragma unroll
      for (int ct = 0; ct < 2; ct++) {
        float x = fmaxf(acc[rt][ct][reg], 0.f);
        s = fmaf(x, x, s);
      }
      p[rt][reg] = s;
    }
  #pragma unroll
  for (int o = 1; o < 16; o <<= 1)
    #pragma unroll
    for (int rt = 0; rt < 2; rt++)
      #pragma unroll
      for (int reg = 0; reg < 4; reg++)
        p[rt][reg] += __shfl_xor(p[rt][reg], o, 64);
  if (m16 == 0) {
    #pragma unroll
    for (int rt = 0; rt < 2; rt++)
      #pragma unroll
      for (int reg = 0; reg < 4; reg++)
        ssq[wid][rt * 16 + kg * 4 + reg] = p[rt][reg];
  }
  __syncthreads();
  #pragma unroll
  for (int rt = 0; rt < 2; rt++) {
    #pragma unroll
    for (int reg = 0; reg < 4; reg++) {
      int row = rt * 16 + kg * 4 + reg;
      float ss = 0.f;
      #pragma unroll
      for (int ww = 0; ww < 8; ww++) ss += ssq[ww][row];
      float inv = 1.f / fmaxf(sqrtf(ss), 1e-12f);
      #pragma unroll
      for (int ct = 0; ct < 2; ct++) {
        int col = wc + ct * 16 + m16;
        out[(size_t)(rb + row) * DD + col] = fmaxf(acc[rt][ct][reg], 0.f) * inv;
      }
    }
  }
}

// ---------------------------------------------------------------- decode
__global__ __launch_bounds__(256) void kDec(const float* __restrict__ h,
                                            const int* __restrict__ aidx,
                                            const float* __restrict__ W4,
                                            const float* __restrict__ W5,
                                            float* __restrict__ Q) {
  __shared__ float tmp[4];
  int b = blockIdx.x, j = threadIdx.x;
  float s = blockSum256(h[(size_t)(NN + b) * DD + j] * W4[j], tmp);
  int a = aidx[b];
  float za = h[(size_t)a * DD + j];
  float q = blockSum256(fmaxf(za * s, 0.f) * W5[j], tmp);
  if (j == 0) Q[b] = q;
}

// ---------------------------------------------------------------- launcher
extern "C" void kernel_launch(void* const* d_in, const int* in_sizes, int n_in,
                              void* d_out, int out_size, void* d_ws, size_t ws_size,
                              hipStream_t stream) {
  (void)in_sizes; (void)n_in; (void)out_size; (void)ws_size;
  const int*   edge_src = (const int*)d_in[0];
  const int*   edge_dst = (const int*)d_in[1];
  const float* edge_w   = (const float*)d_in[2];
  const int*   bassign  = (const int*)d_in[3];
  const int*   aidx     = (const int*)d_in[4];
  const float* Xf       = (const float*)d_in[5];
  const float* Xs       = (const float*)d_in[6];
  const float* W1       = (const float*)d_in[7];
  const float* W2       = (const float*)d_in[8];
  const float* W3       = (const float*)d_in[9];
  const float* linW     = (const float*)d_in[10];
  const float* linB     = (const float*)d_in[11];
  const float* W4       = (const float*)d_in[12];
  const float* W5       = (const float*)d_in[13];
  float* Q = (float*)d_out;

  char* base = (char*)d_ws;
  const size_t NB = (size_t)NT * DD * 4;   // rows include hs
  float* hA   = (float*)(base);
  float* hnv  = (float*)(base + NB);
  float* hB   = (float*)(base + 2 * NB);
  size_t o = 3 * NB;
  short* Bf   = (short*)(base + o); o += (size_t)DD * 512 * 2 * 2;  // 512 KB, fragment order
  long long* sedge = (long long*)(base + o); o += (size_t)EE * 8;
  int*   snode= (int*)(base + o);   o += (size_t)NN * 4;
  int*   rank = (int*)(base + o);   o += (size_t)EE * 4;
  int*   rankB= (int*)(base + o);   o += (size_t)NN * 4;
  int*   offn = (int*)(base + o);   o += (size_t)(NN + 4) * 4;
  int*   offb = (int*)(base + o);   o += (size_t)(BB + 4) * 4;
  int*   curn = (int*)(base + o);   o += (size_t)NN * 4;
  int*   curb = (int*)(base + o);   o += (size_t)BB * 4;   // contiguous with curn

  hipMemsetAsync(curn, 0, (size_t)(NN + BB) * 4, stream);

  kPre<<<NCB + 512 + NT / 4, 256, 0, stream>>>(Xf, Xs, W1, hA,
                                               edge_dst, bassign, curn, curb,
                                               rank, rankB,
                                               W2, W3, linW, Bf);
  kScan<<<1, 1024, 0, stream>>>(curn, offn, curb, offb);
  kPlace<<<(EE + 255) / 256, 256, 0, stream>>>(edge_src, edge_dst, edge_w, bassign,
                                               offn, offb, rank, rankB, sedge, snode);
  float* hc = hA;
  float* hn = hB;
  for (int d = 0; d < DEPTH; d++) {
    kAgg<<<8 * (NT / 8), 512, 0, stream>>>(hc, offn, sedge, offb, snode, hnv);
    kUpdM<<<NT / TRU, 512, 0, stream>>>(hc, hnv, Bf, linB, hn);
    float* sw2 = hc; hc = hn; hn = sw2;
  }
  kDec<<<BB, 256, 0, stream>>>(hc, aidx, W4, W5, Q);
}